// Round 14
// baseline (910.828 us; speedup 1.0000x reference)
//
#include <hip/hip_runtime.h>
#include <hip/hip_bf16.h>

// RNN: S=128, B=64, E=512, H=1024, V=10000, L=2.  M = S*B = 8192.
// prep -> GEMM X0 -> ONE persistent kernel:
//   blocks 0..127   : layer-0 recurrence (Hh0[t] -> Hh0[t+1])
//   blocks 128..383 : layer-1 recurrence (Hh0[s+1]+Hh1[s] -> Hh1[s+1])
//   blocks 384..1023: logits workers (work-queue, gated per timestep-pair)
// Base = R13 (903us).  R14 deltas (control-flow only):
//   (1) s_setprio(1) on recurrence blocks — they share CUs with logits
//       blocks whose continuous MFMA/VMEM issue delays recurrence waves;
//       priority removes that straggler source (T5 regime: role-diverse
//       waves on one CU).  Isolated this time (R11's test was confounded
//       by a simultaneous spill regression).
//   (2) L1 barrier trim: epilogue->publish and drain->RMW are wave-0-only
//       chains (LDS ops in-order within a wave; publishers are tid<64;
//       RMW is tid0) — the two __syncthreads between them order nothing.
//       L0 keeps all barriers (its publish is cross-wave).
// Protocol invariant unchanged (validated R5/6/8/13): data stores drained
// per-wave (vmcnt0) before the RMW; tid0 RMW round-trip precedes done
// visibility; consumers poll done then read data with relaxed agent loads.

typedef unsigned short u16;
typedef unsigned int   u32;
typedef unsigned long long u64;
typedef __bf16 bf16x8 __attribute__((ext_vector_type(8)));
typedef float  f32x4  __attribute__((ext_vector_type(4)));

__device__ __forceinline__ u16 f2b(float f) {
  __hip_bfloat16 h = __float2bfloat16(f);
  return __builtin_bit_cast(u16, h);
}
__device__ __forceinline__ float b2f(u16 u) {
  return __bfloat162float(__builtin_bit_cast(__hip_bfloat16, u));
}

__device__ __forceinline__ void gload16(const void* g, void* lds) {
  __builtin_amdgcn_global_load_lds(
      (const __attribute__((address_space(1))) u32*)g,
      (__attribute__((address_space(3))) u32*)lds, 16, 0, 0);
}

__device__ __forceinline__ u64 aload64(const u64* p) {
  return __hip_atomic_load(p, __ATOMIC_RELAXED, __HIP_MEMORY_SCOPE_AGENT);
}
__device__ __forceinline__ void astore64(u64* p, u64 v) {
  __hip_atomic_store(p, v, __ATOMIC_RELAXED, __HIP_MEMORY_SCOPE_AGENT);
}
__device__ __forceinline__ int aloadi(const int* p) {
  return __hip_atomic_load(p, __ATOMIC_RELAXED, __HIP_MEMORY_SCOPE_AGENT);
}
__device__ __forceinline__ void astorei(int* p, int v) {
  __hip_atomic_store(p, v, __ATOMIC_RELAXED, __HIP_MEMORY_SCOPE_AGENT);
}
__device__ __forceinline__ int afetchadd(int* p) {
  return __hip_atomic_fetch_add(p, 1, __ATOMIC_RELAXED,
                                __HIP_MEMORY_SCOPE_AGENT);
}

// Stage 16 rows x 2048B from src (agent-scope, coalesced: consecutive tids
// read consecutive 8B) into LDS with XOR swizzle byte^=((row&7)<<4).
__device__ __forceinline__ void stage16(char* hbuf, const u64* src, int tid) {
#pragma unroll
  for (int half = 0; half < 2; ++half) {
    u64 tmp[8];
#pragma unroll
    for (int i = 0; i < 8; ++i)
      tmp[i] = aload64(src + (half * 8 + i) * 256 + tid);
#pragma unroll
    for (int i = 0; i < 8; ++i) {
      int it = half * 8 + i;
      *(u64*)(hbuf + it * 2048 + ((tid * 8) ^ ((it & 7) << 4))) = tmp[i];
    }
  }
}

// ---------------------------------------------------------------- prep
__device__ __forceinline__ void cvt4(const float* __restrict__ s,
                                     u16* __restrict__ d, int n4,
                                     int gid, int stride) {
  for (int i = gid; i < n4; i += stride) {
    float4 f = ((const float4*)s)[i];
    ushort4 u;
    u.x = f2b(f.x); u.y = f2b(f.y); u.z = f2b(f.z); u.w = f2b(f.w);
    ((ushort4*)d)[i] = u;
  }
}

__global__ __launch_bounds__(256) void prep_kernel(
    const int* __restrict__ inputs, const float* __restrict__ hidden,
    const float* __restrict__ emb,
    const float* __restrict__ Wx0, const float* __restrict__ Wh0,
    const float* __restrict__ Wx1, const float* __restrict__ Wh1,
    const float* __restrict__ Wout,
    u16* Wx0b, u16* Wh0b, u16* Wcat1, u16* Woutb,
    u16* A0b, u16* Hh0, u16* Hh1, int* flags) {
  int gid = blockIdx.x * 256 + threadIdx.x;
  int stride = gridDim.x * 256;
  if (gid < 1024) flags[gid] = 0;
  cvt4(Wx0, Wx0b, 1024 * 512 / 4, gid, stride);
  cvt4(Wh0, Wh0b, 1024 * 1024 / 4, gid, stride);
  cvt4(Wout, Woutb, 10000 * 1024 / 4, gid, stride);
  cvt4(hidden, Hh0, 65536 / 4, gid, stride);            // slot 0 = h0 init
  cvt4(hidden + 65536, Hh1, 65536 / 4, gid, stride);    // slot 0 = h1 init
  // Wcat1[c][0..1023]=Wx1[c][:], [1024..2047]=Wh1[c][:]
  for (int i = gid; i < 1024 * 512; i += stride) {
    int row = i >> 9, j = i & 511;
    float4 f = (j < 256) ? ((const float4*)Wx1)[row * 256 + j]
                         : ((const float4*)Wh1)[row * 256 + (j - 256)];
    ushort4 u;
    u.x = f2b(f.x); u.y = f2b(f.y); u.z = f2b(f.z); u.w = f2b(f.w);
    ((ushort4*)Wcat1)[i] = u;
  }
  // embedding gather -> bf16 A0 (8192 x 512)
  for (int i = gid; i < 8192 * 128; i += stride) {
    int m = i >> 7, e4 = i & 127;
    int r = inputs[m];
    float4 f = ((const float4*)(emb + (size_t)r * 512))[e4];
    ushort4 u;
    u.x = f2b(f.x); u.y = f2b(f.y); u.z = f2b(f.z); u.w = f2b(f.w);
    ((ushort4*)A0b)[i] = u;
  }
}

// ---------------------------------------------------------------- GEMM (X0)
__global__ __launch_bounds__(256) void gemm_bt(
    const u16* __restrict__ A, const u16* __restrict__ Bm,
    const float* __restrict__ bias, u16* __restrict__ Cout,
    int M, int N, int K) {
  const int tid = threadIdx.x;
  const int l = tid & 63;
  const int wv = tid >> 6;
  const int MT = M >> 7;
  const int bm = (int)blockIdx.x % MT;
  const int bn = (int)blockIdx.x / MT;
  const int m0 = bm * 128, n0 = bn * 128;

  __shared__ u16 As[128 * 32];
  __shared__ u16 Bs[128 * 32];

  const int fa0 = wv * 1024 + l * 16;
  const int fa1 = (4 + wv) * 1024 + l * 16;
  const int rowA0 = fa0 >> 6, kO0 = (fa0 & 63) >> 1;
  const int rowA1 = fa1 >> 6, kO1 = (fa1 & 63) >> 1;
  const u16* gA0 = A + (size_t)(m0 + rowA0) * K + kO0;
  const u16* gA1 = A + (size_t)(m0 + rowA1) * K + kO1;
  const u16* gB0 = Bm + (size_t)(n0 + rowA0) * K + kO0;
  const u16* gB1 = Bm + (size_t)(n0 + rowA1) * K + kO1;
  u16* lA0 = As + wv * 512;
  u16* lA1 = As + (4 + wv) * 512;
  u16* lB0 = Bs + wv * 512;
  u16* lB1 = Bs + (4 + wv) * 512;

  const int wm = wv >> 1, wn = wv & 1;
  const u16* pA = As + (wm * 64 + (l & 15)) * 32 + (l >> 4) * 8;
  const u16* pB = Bs + (wn * 64 + (l & 15)) * 32 + (l >> 4) * 8;

  f32x4 acc[4][4] = {};

  for (int k0 = 0; k0 < K; k0 += 32) {
    __syncthreads();
    gload16(gA0 + k0, lA0);
    gload16(gA1 + k0, lA1);
    gload16(gB0 + k0, lB0);
    gload16(gB1 + k0, lB1);
    asm volatile("s_waitcnt vmcnt(0)" ::: "memory");
    __syncthreads();
    bf16x8 a[4], b[4];
#pragma unroll
    for (int i = 0; i < 4; ++i) a[i] = *(const bf16x8*)(pA + i * 512);
#pragma unroll
    for (int j = 0; j < 4; ++j) b[j] = *(const bf16x8*)(pB + j * 512);
#pragma unroll
    for (int i = 0; i < 4; ++i)
#pragma unroll
      for (int j = 0; j < 4; ++j)
        acc[i][j] = __builtin_amdgcn_mfma_f32_16x16x32_bf16(a[i], b[j],
                                                            acc[i][j], 0, 0, 0);
  }

#pragma unroll
  for (int j = 0; j < 4; ++j) {
    int cn = n0 + wn * 64 + j * 16 + (l & 15);
    float bv = bias[cn];
#pragma unroll
    for (int i = 0; i < 4; ++i) {
      int rmb = m0 + wm * 64 + i * 16 + ((l >> 4) << 2);
#pragma unroll
      for (int r = 0; r < 4; ++r)
        Cout[(size_t)(rmb + r) * N + cn] = f2b(acc[i][j][r] + bv);
    }
  }
}

// ------------------------------------------------ persistent fused kernel
// flags layout (ints, 64B lines):  cnt0[bg]=+0, done0[bg]=+64,
//   cnt1a[bg]=+128, cnt1b[bg]=+192, done1a[bg]=+256, done1b[bg]=+320,
//   workq=+384, dloga[bg]=+448, dlogb[bg]=+512   (bg index << 4)
__global__ __launch_bounds__(256, 4) void rnn_fused(
    const u16* __restrict__ X0, const u16* __restrict__ Wh0b,
    const u16* __restrict__ Wcat1, const float* __restrict__ bh1,
    u16* __restrict__ Hh0, u16* __restrict__ Hh1,
    const u16* __restrict__ Woutb, const float* __restrict__ bout,
    float* __restrict__ outL,
    float* __restrict__ hfin0, float* __restrict__ hfin1,
    int* __restrict__ flags) {
  __shared__ __align__(16) char smem[36928];
  const int tid = threadIdx.x;
  const int l = tid & 63;
  const int wv = tid >> 6;

  if (blockIdx.x < 128) {
    // ---------------- layer 0 (R8 structure + setprio)
    __builtin_amdgcn_s_setprio(1);
    char* hbuf = smem;                                    // 32 KB staged h
    float (*red)[16][16] = (float(*)[16][16])(smem + 32768);
    u16* ht = (u16*)(smem + 35840);
    const int wg = (int)blockIdx.x;
    const int bg = wg & 3, cc = wg >> 2;
    const int cw = wv & 1, kw = wv >> 1;
    const int col = cc * 32 + cw * 16 + (l & 15);
    const int row = l & 15;
    const int sw = (row & 7) << 4;
    const int rowoff = row * 2048;
    const int kwbase = kw * 1024 + ((l >> 4) << 4);
    bf16x8 b[16];
    {
      const u16* wp = Wh0b + (size_t)col * 1024 + (kw * 512 + ((l >> 4) * 8));
#pragma unroll
      for (int kt = 0; kt < 16; ++kt) b[kt] = *(const bf16x8*)(wp + kt * 32);
    }
    int* cnt0 = flags + (bg << 4);
    int* done0 = flags + 64 + (bg << 4);

    for (int t = 0; t < 128; ++t) {
      float xv[4];
      if (kw == 0) {
#pragma unroll
        for (int r = 0; r < 4; ++r) {
          int bat = bg * 16 + (l >> 4) * 4 + r;
          xv[r] = b2f(X0[(size_t)(t * 64 + bat) * 1024 + col]);
        }
      }
      // stage h[t] (coalesced, swizzled)
      stage16(hbuf, (const u64*)(Hh0 + ((size_t)t * 64 + bg * 16) * 1024), tid);
      __syncthreads();
      f32x4 acc = {0.f, 0.f, 0.f, 0.f};
#pragma unroll
      for (int kt = 0; kt < 16; ++kt) {
        bf16x8 av =
            *(const bf16x8*)(hbuf + rowoff + ((kwbase + kt * 64) ^ sw));
        acc = __builtin_amdgcn_mfma_f32_16x16x32_bf16(av, b[kt], acc, 0, 0, 0);
      }
      if (kw == 1) {
#pragma unroll
        for (int r = 0; r < 4; ++r) red[cw][(l >> 4) * 4 + r][l & 15] = acc[r];
      }
      __syncthreads();
      if (kw == 0) {
#pragma unroll
        for (int r = 0; r < 4; ++r) {
          int br = (l >> 4) * 4 + r;
          float v = acc[r] + red[cw][br][l & 15] + xv[r];
          v = tanhf(v);
          ht[br * 32 + cw * 16 + (l & 15)] = f2b(v);
          if (t == 127) hfin0[(bg * 16 + br) * 1024 + col] = v;
        }
      }
      __syncthreads();
      if (tid < 128) {  // publish 16 rows x 64B into Hh0[t+1]
        int rw = tid >> 3, seg = tid & 7;
        u64 v = ((const u64*)ht)[tid];
        u64* dp = (u64*)(Hh0 + ((size_t)(t + 1) * 64 + bg * 16 + rw) * 1024 +
                         cc * 32) + seg;
        astore64(dp, v);
      }
      asm volatile("s_waitcnt vmcnt(0)" ::: "memory");
      __syncthreads();  // all waves' publishes drained (cross-wave publish)
      if (tid == 0) {
        int old = afetchadd(cnt0);
        if (old == (t + 1) * 32 - 1) {
          astorei(done0, t + 1);   // winner broadcast
        } else if (t < 127) {
          while (aloadi(done0) < t + 1) __builtin_amdgcn_s_sleep(1);
        }
      }
      __syncthreads();
    }
  } else if (blockIdx.x < 384) {
    // ---------------- layer 1 (K = 2048 concat: h0[s] then h1[s-1])
    __builtin_amdgcn_s_setprio(1);
    char* hbuf = smem;                                    // 32 KB, two-phase
    float (*red)[16][16] = (float(*)[16][16])(smem + 32768);
    u16* ht = (u16*)(smem + 35840);
    const int wg = (int)blockIdx.x - 128;
    const int bg = wg & 3, cc = wg >> 2;       // cc 0..63
    const int kw = wv;                          // 0..3
    const int col = cc * 16 + (l & 15);
    const int row = l & 15;
    const int sw = (row & 7) << 4;
    const int rowoff = row * 2048;
    const int kwb = (kw & 1) * 1024 + ((l >> 4) << 4);  // within 16-row buf
    bf16x8 b[16];
    {
      const u16* wp = Wcat1 + (size_t)col * 2048 + (kw * 512 + ((l >> 4) * 8));
#pragma unroll
      for (int kt = 0; kt < 16; ++kt) b[kt] = *(const bf16x8*)(wp + kt * 32);
    }
    const float bias = bh1[col];
    int* done0 = flags + 64 + (bg << 4);
    int* cnt1 = flags + (cc < 32 ? 128 : 192) + (bg << 4);
    int* done1a = flags + 256 + (bg << 4);
    int* done1b = flags + 320 + (bg << 4);
    int* mydone = (cc < 32) ? done1a : done1b;
    int* mydlog = flags + (cc < 32 ? 448 : 512) + (bg << 4);

    for (int s = 0; s < 128; ++s) {
      // gate 1: h0[s] ready?  (L0 free-runs ahead -> usually instant)
      if (tid == 0) {
        while (aloadi(done0) < s + 1) __builtin_amdgcn_s_sleep(1);
      }
      __syncthreads();
      // phase A: stage h0[s] (= Hh0 slot s+1), waves kw<2 compute —
      // runs UNDER the peer-straggler wait (gate 2 below).
      stage16(hbuf, (const u64*)(Hh0 + ((size_t)(s + 1) * 64 + bg * 16) * 1024),
              tid);
      __syncthreads();
      f32x4 acc = {0.f, 0.f, 0.f, 0.f};
      if (kw < 2) {
#pragma unroll
        for (int kt = 0; kt < 16; ++kt) {
          bf16x8 av = *(const bf16x8*)(hbuf + rowoff + ((kwb + kt * 64) ^ sw));
          acc =
              __builtin_amdgcn_mfma_f32_16x16x32_bf16(av, b[kt], acc, 0, 0, 0);
        }
      }
      __syncthreads();  // phase-A readers done
      // gate 2: h1[s-1] complete from ALL peer L1 blocks of this bg
      if (tid == 0) {
        while (aloadi(done1a) < s || aloadi(done1b) < s)
          __builtin_amdgcn_s_sleep(1);
      }
      __syncthreads();
      // phase B: stage h1[s-1] (= Hh1 slot s), waves kw>=2 compute
      stage16(hbuf, (const u64*)(Hh1 + ((size_t)s * 64 + bg * 16) * 1024), tid);
      __syncthreads();
      if (kw >= 2) {
#pragma unroll
        for (int kt = 0; kt < 16; ++kt) {
          bf16x8 av = *(const bf16x8*)(hbuf + rowoff + ((kwb + kt * 64) ^ sw));
          acc =
              __builtin_amdgcn_mfma_f32_16x16x32_bf16(av, b[kt], acc, 0, 0, 0);
        }
      }
      if (kw != 0) {
#pragma unroll
        for (int r = 0; r < 4; ++r)
          red[kw - 1][(l >> 4) * 4 + r][l & 15] = acc[r];
      }
      __syncthreads();
      // epilogue + publish + RMW: ALL wave-0-local from here (LDS ops are
      // in-order within a wave; publishers are tid<64; RMW is tid0) —
      // the two intervening barriers of R13 removed.
      if (kw == 0) {
#pragma unroll
        for (int r = 0; r < 4; ++r) {
          int br = (l >> 4) * 4 + r;
          int c = l & 15;
          float v = acc[r] + red[0][br][c] + red[1][br][c] + red[2][br][c] +
                    bias;
          v = tanhf(v);
          ht[br * 16 + c] = f2b(v);
          if (s == 127) hfin1[(bg * 16 + br) * 1024 + col] = v;
        }
      }
      if (tid < 64) {  // publish 16 rows x 32B into Hh1[s+1]
        int rw = tid >> 2, seg = tid & 3;
        u64 v = ((const u64*)ht)[tid];
        u64* dp = (u64*)(Hh1 + ((size_t)(s + 1) * 64 + bg * 16 + rw) * 1024 +
                         cc * 16) + seg;
        astore64(dp, v);
      }
      asm volatile("s_waitcnt vmcnt(0)" ::: "memory");
      if (tid == 0) {
        int old = afetchadd(cnt1);
        if (old == (s + 1) * 32 - 1) {
          astorei(mydone, s + 1);   // for L1 peers (64 pollers only)
          astorei(mydlog, s + 1);   // for logits workers (separate line)
        }
      }
    }
  } else {
    // ---------------- logits workers: C[8192,10000] = Hh1[1..] @ Wout^T + b
    u16* As = (u16*)smem;
    u16* Bs = (u16*)(smem + 8192);
    int* shid = (int*)(smem + 16384);
    int* workq = flags + 384;
    int* dla = flags + 448;
    int* dlb = flags + 512;

    const int fa0 = wv * 1024 + l * 16;
    const int fa1 = (4 + wv) * 1024 + l * 16;
    const int rowA0 = fa0 >> 6, kO0 = (fa0 & 63) >> 1;
    const int rowA1 = fa1 >> 6, kO1 = (fa1 & 63) >> 1;
    const u16* Abase = Hh1 + 65536;  // skip slot 0
    u16* lB0 = Bs + wv * 512;
    u16* lB1 = Bs + (4 + wv) * 512;
    u64* dA0 = (u64*)((char*)As + wv * 1024 + l * 16);
    u64* dA1 = (u64*)((char*)As + (4 + wv) * 1024 + l * 16);
    const int wm = wv >> 1, wn = wv & 1;
    const u16* pA = As + (wm * 64 + (l & 15)) * 32 + (l >> 4) * 8;
    const u16* pB = Bs + (wn * 64 + (l & 15)) * 32 + (l >> 4) * 8;

    for (;;) {
      if (tid == 0)
        *shid = afetchadd(workq);
      __syncthreads();
      const int id = *shid;
      __syncthreads();
      if (id >= 64 * 79) break;
      const int u = id / 79, nn = id - u * 79;
      const int m0 = u * 128, n0 = nn * 128;

      if (tid == 0) {  // gate on dlog mirrors only (coarse backoff)
        const int tgt = 2 * u + 2;
        for (;;) {
          int ok = 1;
#pragma unroll
          for (int g = 0; g < 4; ++g)
            ok &= (aloadi(dla + g * 16) >= tgt) & (aloadi(dlb + g * 16) >= tgt);
          if (ok) break;
          __builtin_amdgcn_s_sleep(32);
        }
      }
      __syncthreads();

      const u16* gA0 = Abase + (size_t)(m0 + rowA0) * 1024 + kO0;
      const u16* gA1 = Abase + (size_t)(m0 + rowA1) * 1024 + kO1;
      int rB0 = n0 + rowA0; if (rB0 >= 10000) rB0 = 9999;
      int rB1 = n0 + rowA1; if (rB1 >= 10000) rB1 = 9999;
      const u16* gB0 = Woutb + (size_t)rB0 * 1024 + kO0;
      const u16* gB1 = Woutb + (size_t)rB1 * 1024 + kO1;

      f32x4 acc[4][4] = {};
      for (int k0 = 0; k0 < 1024; k0 += 32) {
        __syncthreads();
        const u64* pa0 = (const u64*)(gA0 + k0);
        const u64* pa1 = (const u64*)(gA1 + k0);
        u64 a00 = aload64(pa0), a01 = aload64(pa0 + 1);
        u64 a10 = aload64(pa1), a11 = aload64(pa1 + 1);
        gload16(gB0 + k0, lB0);
        gload16(gB1 + k0, lB1);
        dA0[0] = a00; dA0[1] = a01;
        dA1[0] = a10; dA1[1] = a11;
        asm volatile("s_waitcnt vmcnt(0)" ::: "memory");
        __syncthreads();
        bf16x8 a[4], b[4];
#pragma unroll
        for (int i = 0; i < 4; ++i) a[i] = *(const bf16x8*)(pA + i * 512);
#pragma unroll
        for (int j = 0; j < 4; ++j) b[j] = *(const bf16x8*)(pB + j * 512);
#pragma unroll
        for (int i = 0; i < 4; ++i)
#pragma unroll
          for (int j = 0; j < 4; ++j)
            acc[i][j] = __builtin_amdgcn_mfma_f32_16x16x32_bf16(
                a[i], b[j], acc[i][j], 0, 0, 0);
      }
#pragma unroll
      for (int j = 0; j < 4; ++j) {
        int cn = n0 + wn * 64 + j * 16 + (l & 15);
        if (cn >= 10000) continue;
        float bv = bout[cn];
#pragma unroll
        for (int i = 0; i < 4; ++i) {
          int rmb = m0 + wm * 64 + i * 16 + ((l >> 4) << 2);
#pragma unroll
          for (int r = 0; r < 4; ++r)
            outL[(size_t)(rmb + r) * 10000 + cn] = acc[i][j][r] + bv;
        }
      }
    }
  }
}

// ---------------------------------------------------------------- launch
extern "C" void kernel_launch(void* const* d_in, const int* in_sizes, int n_in,
                              void* d_out, int out_size, void* d_ws,
                              size_t ws_size, hipStream_t stream) {
  const int*   inputs = (const int*)d_in[0];
  const float* hidden = (const float*)d_in[1];
  const float* emb    = (const float*)d_in[2];
  const float* Wx0    = (const float*)d_in[3];
  const float* Wh0    = (const float*)d_in[4];
  const float* bh0    = (const float*)d_in[5];
  const float* Wx1    = (const float*)d_in[6];
  const float* Wh1    = (const float*)d_in[7];
  const float* bh1    = (const float*)d_in[8];
  const float* Wout   = (const float*)d_in[9];
  const float* bout   = (const float*)d_in[10];
  float* out = (float*)d_out;

  if (ws_size < (size_t)88 * 1024 * 1024) return;

  char* w = (char*)d_ws;
  u16* Wx0b  = (u16*)w; w += 1048576;     // 1024x512
  u16* Wh0b  = (u16*)w; w += 2097152;     // 1024x1024
  u16* Wcat1 = (u16*)w; w += 4194304;     // 1024x2048
  u16* Woutb = (u16*)w; w += 20480000;    // 10000x1024
  u16* A0b   = (u16*)w; w += 8388608;     // 8192x512
  u16* X0b   = (u16*)w; w += 16777216;    // 8192x1024
  u16* Hh0   = (u16*)w; w += 16908288;    // 129x64x1024
  u16* Hh1   = (u16*)w; w += 16908288;    // 129x64x1024
  int* flags = (int*)w;                   // 1024 ints (flag lines + workq)

  float* hfin0 = out + 81920000;
  float* hfin1 = out + 81920000 + 65536;

  prep_kernel<<<2048, 256, 0, stream>>>(inputs, hidden, emb, Wx0, Wh0, Wx1,
                                        Wh1, Wout, Wx0b, Wh0b, Wcat1, Woutb,
                                        A0b, Hh0, Hh1, flags);
  // X0 = emb_gathered @ Wx0^T + bh0   (8192 x 1024, K=512)
  gemm_bt<<<512, 256, 0, stream>>>(A0b, Wx0b, bh0, X0b, 8192, 1024, 512);
  // persistent: 2-layer recurrence + overlapped logits GEMM
  rnn_fused<<<1024, 256, 0, stream>>>(X0b, Wh0b, Wcat1, bh1, Hh0, Hh1, Woutb,
                                      bout, out, hfin0, hfin1, flags);
}

// Round 15
// 828.088 us; speedup vs baseline: 1.0999x; 1.0999x over previous
//
#include <hip/hip_runtime.h>
#include <hip/hip_bf16.h>

// RNN: S=128, B=64, E=512, H=1024, V=10000, L=2.  M = S*B = 8192.
// prep -> GEMM X0 -> ONE persistent kernel (512 blocks x 512 threads, 2/CU):
//   blocks 0..63    : layer-0, 64 cols/block (16 blocks/bg, fan-in 16)
//   blocks 64..191  : layer-1, 32 cols/block (32 blocks/bg, fan-in 32)
//   blocks 192..511 : logits workers, 2 independent 4-wave sub-workers each
// R15: halve gate fan-in + h-staging traffic via 8-wave blocks while
// keeping PER-THREAD code identical to R13 (each thread still owns one
// 16-col x K-slice b[16] fragment — the R9-R12 VGPR failure mode is
// avoided by construction).  One 32KB h-stage now feeds 2x the MFMA.
// Protocol invariant (validated R5/6/8/13): publish stores drained
// per-wave (vmcnt0) + barrier before tid0's RMW; RMW round-trip precedes
// done visibility; consumers poll done (tid0 only), read relaxed agent.

typedef unsigned short u16;
typedef unsigned int   u32;
typedef unsigned long long u64;
typedef __bf16 bf16x8 __attribute__((ext_vector_type(8)));
typedef float  f32x4  __attribute__((ext_vector_type(4)));

__device__ __forceinline__ u16 f2b(float f) {
  __hip_bfloat16 h = __float2bfloat16(f);
  return __builtin_bit_cast(u16, h);
}
__device__ __forceinline__ float b2f(u16 u) {
  return __bfloat162float(__builtin_bit_cast(__hip_bfloat16, u));
}

__device__ __forceinline__ void gload16(const void* g, void* lds) {
  __builtin_amdgcn_global_load_lds(
      (const __attribute__((address_space(1))) u32*)g,
      (__attribute__((address_space(3))) u32*)lds, 16, 0, 0);
}

__device__ __forceinline__ u64 aload64(const u64* p) {
  return __hip_atomic_load(p, __ATOMIC_RELAXED, __HIP_MEMORY_SCOPE_AGENT);
}
__device__ __forceinline__ void astore64(u64* p, u64 v) {
  __hip_atomic_store(p, v, __ATOMIC_RELAXED, __HIP_MEMORY_SCOPE_AGENT);
}
__device__ __forceinline__ int aloadi(const int* p) {
  return __hip_atomic_load(p, __ATOMIC_RELAXED, __HIP_MEMORY_SCOPE_AGENT);
}
__device__ __forceinline__ void astorei(int* p, int v) {
  __hip_atomic_store(p, v, __ATOMIC_RELAXED, __HIP_MEMORY_SCOPE_AGENT);
}
__device__ __forceinline__ int afetchadd(int* p) {
  return __hip_atomic_fetch_add(p, 1, __ATOMIC_RELAXED,
                                __HIP_MEMORY_SCOPE_AGENT);
}

// Stage 16 rows x 2048B with 512 threads (coalesced agent loads; XOR
// swizzle byte^=((row&7)<<4)).  8 loads/thread, 2 rows per step.
__device__ __forceinline__ void stage16_512(char* hbuf, const u64* src,
                                            int tid) {
  const int rsub = tid >> 8;       // 0..1
  const int coff = tid & 255;      // u64 within row
#pragma unroll
  for (int half = 0; half < 2; ++half) {
    u64 tmp[4];
#pragma unroll
    for (int i = 0; i < 4; ++i) {
      int it = half * 8 + i * 2 + rsub;
      tmp[i] = aload64(src + it * 256 + coff);
    }
#pragma unroll
    for (int i = 0; i < 4; ++i) {
      int it = half * 8 + i * 2 + rsub;
      *(u64*)(hbuf + it * 2048 + ((coff * 8) ^ ((it & 7) << 4))) = tmp[i];
    }
  }
}

// ---------------------------------------------------------------- prep
__device__ __forceinline__ void cvt4(const float* __restrict__ s,
                                     u16* __restrict__ d, int n4,
                                     int gid, int stride) {
  for (int i = gid; i < n4; i += stride) {
    float4 f = ((const float4*)s)[i];
    ushort4 u;
    u.x = f2b(f.x); u.y = f2b(f.y); u.z = f2b(f.z); u.w = f2b(f.w);
    ((ushort4*)d)[i] = u;
  }
}

__global__ __launch_bounds__(256) void prep_kernel(
    const int* __restrict__ inputs, const float* __restrict__ hidden,
    const float* __restrict__ emb,
    const float* __restrict__ Wx0, const float* __restrict__ Wh0,
    const float* __restrict__ Wx1, const float* __restrict__ Wh1,
    const float* __restrict__ Wout,
    u16* Wx0b, u16* Wh0b, u16* Wcat1, u16* Woutb,
    u16* A0b, u16* Hh0, u16* Hh1, int* flags) {
  int gid = blockIdx.x * 256 + threadIdx.x;
  int stride = gridDim.x * 256;
  if (gid < 1024) flags[gid] = 0;
  cvt4(Wx0, Wx0b, 1024 * 512 / 4, gid, stride);
  cvt4(Wh0, Wh0b, 1024 * 1024 / 4, gid, stride);
  cvt4(Wout, Woutb, 10000 * 1024 / 4, gid, stride);
  cvt4(hidden, Hh0, 65536 / 4, gid, stride);            // slot 0 = h0 init
  cvt4(hidden + 65536, Hh1, 65536 / 4, gid, stride);    // slot 0 = h1 init
  // Wcat1[c][0..1023]=Wx1[c][:], [1024..2047]=Wh1[c][:]
  for (int i = gid; i < 1024 * 512; i += stride) {
    int row = i >> 9, j = i & 511;
    float4 f = (j < 256) ? ((const float4*)Wx1)[row * 256 + j]
                         : ((const float4*)Wh1)[row * 256 + (j - 256)];
    ushort4 u;
    u.x = f2b(f.x); u.y = f2b(f.y); u.z = f2b(f.z); u.w = f2b(f.w);
    ((ushort4*)Wcat1)[i] = u;
  }
  // embedding gather -> bf16 A0 (8192 x 512)
  for (int i = gid; i < 8192 * 128; i += stride) {
    int m = i >> 7, e4 = i & 127;
    int r = inputs[m];
    float4 f = ((const float4*)(emb + (size_t)r * 512))[e4];
    ushort4 u;
    u.x = f2b(f.x); u.y = f2b(f.y); u.z = f2b(f.z); u.w = f2b(f.w);
    ((ushort4*)A0b)[i] = u;
  }
}

// ---------------------------------------------------------------- GEMM (X0)
__global__ __launch_bounds__(256) void gemm_bt(
    const u16* __restrict__ A, const u16* __restrict__ Bm,
    const float* __restrict__ bias, u16* __restrict__ Cout,
    int M, int N, int K) {
  const int tid = threadIdx.x;
  const int l = tid & 63;
  const int wv = tid >> 6;
  const int MT = M >> 7;
  const int bm = (int)blockIdx.x % MT;
  const int bn = (int)blockIdx.x / MT;
  const int m0 = bm * 128, n0 = bn * 128;

  __shared__ u16 As[128 * 32];
  __shared__ u16 Bs[128 * 32];

  const int fa0 = wv * 1024 + l * 16;
  const int fa1 = (4 + wv) * 1024 + l * 16;
  const int rowA0 = fa0 >> 6, kO0 = (fa0 & 63) >> 1;
  const int rowA1 = fa1 >> 6, kO1 = (fa1 & 63) >> 1;
  const u16* gA0 = A + (size_t)(m0 + rowA0) * K + kO0;
  const u16* gA1 = A + (size_t)(m0 + rowA1) * K + kO1;
  const u16* gB0 = Bm + (size_t)(n0 + rowA0) * K + kO0;
  const u16* gB1 = Bm + (size_t)(n0 + rowA1) * K + kO1;
  u16* lA0 = As + wv * 512;
  u16* lA1 = As + (4 + wv) * 512;
  u16* lB0 = Bs + wv * 512;
  u16* lB1 = Bs + (4 + wv) * 512;

  const int wm = wv >> 1, wn = wv & 1;
  const u16* pA = As + (wm * 64 + (l & 15)) * 32 + (l >> 4) * 8;
  const u16* pB = Bs + (wn * 64 + (l & 15)) * 32 + (l >> 4) * 8;

  f32x4 acc[4][4] = {};

  for (int k0 = 0; k0 < K; k0 += 32) {
    __syncthreads();
    gload16(gA0 + k0, lA0);
    gload16(gA1 + k0, lA1);
    gload16(gB0 + k0, lB0);
    gload16(gB1 + k0, lB1);
    asm volatile("s_waitcnt vmcnt(0)" ::: "memory");
    __syncthreads();
    bf16x8 a[4], b[4];
#pragma unroll
    for (int i = 0; i < 4; ++i) a[i] = *(const bf16x8*)(pA + i * 512);
#pragma unroll
    for (int j = 0; j < 4; ++j) b[j] = *(const bf16x8*)(pB + j * 512);
#pragma unroll
    for (int i = 0; i < 4; ++i)
#pragma unroll
      for (int j = 0; j < 4; ++j)
        acc[i][j] = __builtin_amdgcn_mfma_f32_16x16x32_bf16(a[i], b[j],
                                                            acc[i][j], 0, 0, 0);
  }

#pragma unroll
  for (int j = 0; j < 4; ++j) {
    int cn = n0 + wn * 64 + j * 16 + (l & 15);
    float bv = bias[cn];
#pragma unroll
    for (int i = 0; i < 4; ++i) {
      int rmb = m0 + wm * 64 + i * 16 + ((l >> 4) << 2);
#pragma unroll
      for (int r = 0; r < 4; ++r)
        Cout[(size_t)(rmb + r) * N + cn] = f2b(acc[i][j][r] + bv);
    }
  }
}

// ------------------------------------------------ persistent fused kernel
// flags (ints, 64B lines): cnt0[bg]=+0, done0[bg]=+64, cnt1[bg]=+128,
//   done1[bg]=+256, workq=+384, dlog[bg]=+448   (bg << 4)
__global__ __launch_bounds__(512, 2) void rnn_fused(
    const u16* __restrict__ X0, const u16* __restrict__ Wh0b,
    const u16* __restrict__ Wcat1, const float* __restrict__ bh1,
    u16* __restrict__ Hh0, u16* __restrict__ Hh1,
    const u16* __restrict__ Woutb, const float* __restrict__ bout,
    float* __restrict__ outL,
    float* __restrict__ hfin0, float* __restrict__ hfin1,
    int* __restrict__ flags) {
  __shared__ __align__(16) char smem[40960];
  const int tid = threadIdx.x;
  const int l = tid & 63;
  const int wv = tid >> 6;       // 0..7

  if (blockIdx.x < 64) {
    // ---------------- layer 0: 64 cols/block, 16 blocks/bg
    char* hbuf = smem;                                     // 32 KB
    float (*red)[16][16] = (float(*)[16][16])(smem + 32768);  // [4][16][16]
    u16* ht = (u16*)(smem + 38912);                        // 16x64 bf16
    const int wg = (int)blockIdx.x;
    const int bg = wg & 3, cc = wg >> 2;    // cc 0..15
    const int cw = wv & 3, kw = wv >> 2;    // col-quarter, K-half
    const int col = cc * 64 + cw * 16 + (l & 15);
    const int row = l & 15;
    const int sw = (row & 7) << 4;
    const int rowoff = row * 2048;
    const int kwbase = kw * 1024 + ((l >> 4) << 4);
    bf16x8 b[16];
    {
      const u16* wp = Wh0b + (size_t)col * 1024 + (kw * 512 + ((l >> 4) * 8));
#pragma unroll
      for (int kt = 0; kt < 16; ++kt) b[kt] = *(const bf16x8*)(wp + kt * 32);
    }
    int* cnt0 = flags + (bg << 4);
    int* done0 = flags + 64 + (bg << 4);

    for (int t = 0; t < 128; ++t) {
      float xv[4];
      if (kw == 0) {
#pragma unroll
        for (int r = 0; r < 4; ++r) {
          int bat = bg * 16 + (l >> 4) * 4 + r;
          xv[r] = b2f(X0[(size_t)(t * 64 + bat) * 1024 + col]);
        }
      }
      stage16_512(hbuf, (const u64*)(Hh0 + ((size_t)t * 64 + bg * 16) * 1024),
                  tid);
      __syncthreads();
      f32x4 acc = {0.f, 0.f, 0.f, 0.f};
#pragma unroll
      for (int kt = 0; kt < 16; ++kt) {
        bf16x8 av =
            *(const bf16x8*)(hbuf + rowoff + ((kwbase + kt * 64) ^ sw));
        acc = __builtin_amdgcn_mfma_f32_16x16x32_bf16(av, b[kt], acc, 0, 0, 0);
      }
      if (kw == 1) {
#pragma unroll
        for (int r = 0; r < 4; ++r) red[cw][(l >> 4) * 4 + r][l & 15] = acc[r];
      }
      __syncthreads();
      if (kw == 0) {
#pragma unroll
        for (int r = 0; r < 4; ++r) {
          int br = (l >> 4) * 4 + r;
          float v = acc[r] + red[cw][br][l & 15] + xv[r];
          v = tanhf(v);
          ht[br * 64 + cw * 16 + (l & 15)] = f2b(v);
          if (t == 127) hfin0[(bg * 16 + br) * 1024 + col] = v;
        }
      }
      __syncthreads();
      if (tid < 256) {  // publish 16 rows x 128B into Hh0[t+1]
        int rw = tid >> 4, seg = tid & 15;
        u64 v = ((const u64*)ht)[tid];
        u64* dp = (u64*)(Hh0 + ((size_t)(t + 1) * 64 + bg * 16 + rw) * 1024 +
                         cc * 64) + seg;
        astore64(dp, v);
      }
      asm volatile("s_waitcnt vmcnt(0)" ::: "memory");
      __syncthreads();  // all waves' publishes drained
      if (tid == 0) {
        int old = afetchadd(cnt0);
        if (old == (t + 1) * 16 - 1) {
          astorei(done0, t + 1);   // winner broadcast
        } else if (t < 127) {
          while (aloadi(done0) < t + 1) __builtin_amdgcn_s_sleep(1);
        }
      }
      __syncthreads();
    }
  } else if (blockIdx.x < 192) {
    // ---------------- layer 1: 32 cols/block, 32 blocks/bg, K=2048 concat
    char* hbuf = smem;                                     // 32 KB two-phase
    float (*red)[3][16][16] = (float(*)[3][16][16])(smem + 32768);  // [2][..]
    u16* ht = (u16*)(smem + 38912);                        // 16x32 bf16
    const int wg = (int)blockIdx.x - 64;
    const int bg = wg & 3, cc = wg >> 2;    // cc 0..31
    const int ch = wv & 1, kw = wv >> 1;    // col-half, K-quarter 0..3
    const int col = cc * 32 + ch * 16 + (l & 15);
    const int row = l & 15;
    const int sw = (row & 7) << 4;
    const int rowoff = row * 2048;
    const int kwb = (kw & 1) * 1024 + ((l >> 4) << 4);  // within 16-row buf
    bf16x8 b[16];
    {
      const u16* wp = Wcat1 + (size_t)col * 2048 + (kw * 512 + ((l >> 4) * 8));
#pragma unroll
      for (int kt = 0; kt < 16; ++kt) b[kt] = *(const bf16x8*)(wp + kt * 32);
    }
    const float bias = bh1[col];
    int* done0 = flags + 64 + (bg << 4);
    int* cnt1 = flags + 128 + (bg << 4);
    int* done1 = flags + 256 + (bg << 4);
    int* dlog = flags + 448 + (bg << 4);

    for (int s = 0; s < 128; ++s) {
      // gate 1: h0[s] ready (L0 runs ahead -> usually instant)
      if (tid == 0) {
        while (aloadi(done0) < s + 1) __builtin_amdgcn_s_sleep(1);
      }
      __syncthreads();
      // phase A: stage h0[s] (= Hh0 slot s+1); waves kw<2 compute —
      // runs under the peer-straggler wait (gate 2 below).
      stage16_512(hbuf,
                  (const u64*)(Hh0 + ((size_t)(s + 1) * 64 + bg * 16) * 1024),
                  tid);
      __syncthreads();
      f32x4 acc = {0.f, 0.f, 0.f, 0.f};
      if (kw < 2) {
#pragma unroll
        for (int kt = 0; kt < 16; ++kt) {
          bf16x8 av = *(const bf16x8*)(hbuf + rowoff + ((kwb + kt * 64) ^ sw));
          acc =
              __builtin_amdgcn_mfma_f32_16x16x32_bf16(av, b[kt], acc, 0, 0, 0);
        }
      }
      __syncthreads();  // phase-A readers done
      // gate 2: h1[s-1] complete from all 32 peer blocks of this bg
      if (tid == 0) {
        while (aloadi(done1) < s) __builtin_amdgcn_s_sleep(1);
      }
      __syncthreads();
      // phase B: stage h1[s-1] (= Hh1 slot s); waves kw>=2 compute
      stage16_512(hbuf, (const u64*)(Hh1 + ((size_t)s * 64 + bg * 16) * 1024),
                  tid);
      __syncthreads();
      if (kw >= 2) {
#pragma unroll
        for (int kt = 0; kt < 16; ++kt) {
          bf16x8 av = *(const bf16x8*)(hbuf + rowoff + ((kwb + kt * 64) ^ sw));
          acc =
              __builtin_amdgcn_mfma_f32_16x16x32_bf16(av, b[kt], acc, 0, 0, 0);
        }
      }
      if (kw != 0) {
#pragma unroll
        for (int r = 0; r < 4; ++r)
          red[ch][kw - 1][(l >> 4) * 4 + r][l & 15] = acc[r];
      }
      __syncthreads();
      if (kw == 0) {
#pragma unroll
        for (int r = 0; r < 4; ++r) {
          int br = (l >> 4) * 4 + r;
          int c = l & 15;
          float v = acc[r] + red[ch][0][br][c] + red[ch][1][br][c] +
                    red[ch][2][br][c] + bias;
          v = tanhf(v);
          ht[br * 32 + ch * 16 + c] = f2b(v);
          if (s == 127) hfin1[(bg * 16 + br) * 1024 + col] = v;
        }
      }
      __syncthreads();
      if (tid < 128) {  // publish 16 rows x 64B into Hh1[s+1]
        int rw = tid >> 3, seg = tid & 7;
        u64 v = ((const u64*)ht)[tid];
        u64* dp = (u64*)(Hh1 + ((size_t)(s + 1) * 64 + bg * 16 + rw) * 1024 +
                         cc * 32) + seg;
        astore64(dp, v);
      }
      asm volatile("s_waitcnt vmcnt(0)" ::: "memory");
      __syncthreads();
      if (tid == 0) {
        int old = afetchadd(cnt1);
        if (old == (s + 1) * 32 - 1) {
          astorei(done1, s + 1);   // for L1 peers
          astorei(dlog, s + 1);    // for logits workers (separate line)
        }
      }
    }
  } else {
    // ------------- logits: 2 independent 4-wave sub-workers per block
    const int sub = wv >> 2;        // 0..1
    const int wvl = wv & 3;         // wave within sub
    u16* As = (u16*)(smem + sub * 16384);
    u16* Bs = (u16*)(smem + sub * 16384 + 8192);
    int* shid = (int*)(smem + 32768);
    int* workq = flags + 384;
    int* dlg = flags + 448;

    const int fa0 = wvl * 1024 + l * 16;
    const int fa1 = (4 + wvl) * 1024 + l * 16;
    const int rowA0 = fa0 >> 6, kO0 = (fa0 & 63) >> 1;
    const int rowA1 = fa1 >> 6, kO1 = (fa1 & 63) >> 1;
    const u16* Abase = Hh1 + 65536;  // skip slot 0
    u16* lB0 = Bs + wvl * 512;
    u16* lB1 = Bs + (4 + wvl) * 512;
    u64* dA0 = (u64*)((char*)As + wvl * 1024 + l * 16);
    u64* dA1 = (u64*)((char*)As + (4 + wvl) * 1024 + l * 16);
    const int wm = wvl >> 1, wn = wvl & 1;
    const u16* pA = As + (wm * 64 + (l & 15)) * 32 + (l >> 4) * 8;
    const u16* pB = Bs + (wn * 64 + (l & 15)) * 32 + (l >> 4) * 8;

    for (;;) {
      if (tid == 0) *shid = afetchadd(workq);
      __syncthreads();
      const int base = *shid;
      __syncthreads();
      if (base >= 2528) break;           // 5056 tiles / 2
      const int id = base * 2 + sub;
      const int u = id / 79, nn = id - u * 79;
      const int m0 = u * 128, n0 = nn * 128;

      if (tid == 0) {  // gate both subs' tiles: higher id has higher u
        const int uhi = (base * 2 + 1) / 79;
        const int tgt = 2 * uhi + 2;
        for (;;) {
          int ok = 1;
#pragma unroll
          for (int g = 0; g < 4; ++g) ok &= (aloadi(dlg + g * 16) >= tgt);
          if (ok) break;
          __builtin_amdgcn_s_sleep(32);
        }
      }
      __syncthreads();

      const u16* gA0 = Abase + (size_t)(m0 + rowA0) * 1024 + kO0;
      const u16* gA1 = Abase + (size_t)(m0 + rowA1) * 1024 + kO1;
      int rB0 = n0 + rowA0; if (rB0 >= 10000) rB0 = 9999;
      int rB1 = n0 + rowA1; if (rB1 >= 10000) rB1 = 9999;
      const u16* gB0 = Woutb + (size_t)rB0 * 1024 + kO0;
      const u16* gB1 = Woutb + (size_t)rB1 * 1024 + kO1;

      f32x4 acc[4][4] = {};
      for (int k0 = 0; k0 < 1024; k0 += 32) {
        __syncthreads();
        const u64* pa0 = (const u64*)(gA0 + k0);
        const u64* pa1 = (const u64*)(gA1 + k0);
        u64 a00 = aload64(pa0), a01 = aload64(pa0 + 1);
        u64 a10 = aload64(pa1), a11 = aload64(pa1 + 1);
        gload16(gB0 + k0, lB0);
        gload16(gB1 + k0, lB1);
        dA0[0] = a00; dA0[1] = a01;
        dA1[0] = a10; dA1[1] = a11;
        asm volatile("s_waitcnt vmcnt(0)" ::: "memory");
        __syncthreads();
        bf16x8 a[4], b[4];
#pragma unroll
        for (int i = 0; i < 4; ++i) a[i] = *(const bf16x8*)(pA + i * 512);
#pragma unroll
        for (int j = 0; j < 4; ++j) b[j] = *(const bf16x8*)(pB + j * 512);
#pragma unroll
        for (int i = 0; i < 4; ++i)
#pragma unroll
          for (int j = 0; j < 4; ++j)
            acc[i][j] = __builtin_amdgcn_mfma_f32_16x16x32_bf16(
                a[i], b[j], acc[i][j], 0, 0, 0);
      }
#pragma unroll
      for (int j = 0; j < 4; ++j) {
        int cn = n0 + wn * 64 + j * 16 + (l & 15);
        if (cn >= 10000) continue;
        float bv = bout[cn];
#pragma unroll
        for (int i = 0; i < 4; ++i) {
          int rmb = m0 + wm * 64 + i * 16 + ((l >> 4) << 2);
#pragma unroll
          for (int r = 0; r < 4; ++r)
            outL[(size_t)(rmb + r) * 10000 + cn] = acc[i][j][r] + bv;
        }
      }
    }
  }
}

// ---------------------------------------------------------------- launch
extern "C" void kernel_launch(void* const* d_in, const int* in_sizes, int n_in,
                              void* d_out, int out_size, void* d_ws,
                              size_t ws_size, hipStream_t stream) {
  const int*   inputs = (const int*)d_in[0];
  const float* hidden = (const float*)d_in[1];
  const float* emb    = (const float*)d_in[2];
  const float* Wx0    = (const float*)d_in[3];
  const float* Wh0    = (const float*)d_in[4];
  const float* bh0    = (const float*)d_in[5];
  const float* Wx1    = (const float*)d_in[6];
  const float* Wh1    = (const float*)d_in[7];
  const float* bh1    = (const float*)d_in[8];
  const float* Wout   = (const float*)d_in[9];
  const float* bout   = (const float*)d_in[10];
  float* out = (float*)d_out;

  if (ws_size < (size_t)88 * 1024 * 1024) return;

  char* w = (char*)d_ws;
  u16* Wx0b  = (u16*)w; w += 1048576;     // 1024x512
  u16* Wh0b  = (u16*)w; w += 2097152;     // 1024x1024
  u16* Wcat1 = (u16*)w; w += 4194304;     // 1024x2048
  u16* Woutb = (u16*)w; w += 20480000;    // 10000x1024
  u16* A0b   = (u16*)w; w += 8388608;     // 8192x512
  u16* X0b   = (u16*)w; w += 16777216;    // 8192x1024
  u16* Hh0   = (u16*)w; w += 16908288;    // 129x64x1024
  u16* Hh1   = (u16*)w; w += 16908288;    // 129x64x1024
  int* flags = (int*)w;                   // 1024 ints

  float* hfin0 = out + 81920000;
  float* hfin1 = out + 81920000 + 65536;

  prep_kernel<<<2048, 256, 0, stream>>>(inputs, hidden, emb, Wx0, Wh0, Wx1,
                                        Wh1, Wout, Wx0b, Wh0b, Wcat1, Woutb,
                                        A0b, Hh0, Hh1, flags);
  // X0 = emb_gathered @ Wx0^T + bh0   (8192 x 1024, K=512)
  gemm_bt<<<512, 256, 0, stream>>>(A0b, Wx0b, bh0, X0b, 8192, 1024, 512);
  // persistent: 2-layer recurrence + overlapped logits GEMM
  rnn_fused<<<512, 512, 0, stream>>>(X0b, Wh0b, Wcat1, bh1, Hh0, Hh1, Woutb,
                                     bout, out, hfin0, hfin1, flags);
}

// Round 16
// 669.026 us; speedup vs baseline: 1.3614x; 1.2378x over previous
//
#include <hip/hip_runtime.h>
#include <hip/hip_bf16.h>

// RNN: S=128, B=64, E=512, H=1024, V=10000, L=2.  M = S*B = 8192.
// prep -> GEMM X0 -> ONE persistent kernel (256 blocks x 1024 thr, 1/CU):
//   blocks 0..31   : layer-0, 128 cols/block (8 blocks/bg, fan-in 8)
//   blocks 32..95  : layer-1, 64 cols/block (16 blocks/bg, fan-in 16)
//   blocks 96..255 : logits workers, 4 x 4-wave sub-workers, XCD-class
//                    queues (class = blockIdx&7 owns N-tiles n%8==class ->
//                    each XCD L2 keeps its 2.5MB Wout slice resident)
// R16 = R15's proven fan-in-halving lever iterated (16-wave blocks; per-
// thread hot code and reduction order byte-identical) + XCD-affine logits
// to cut IC jitter feeding the straggler spread.
// Protocol invariant (validated R5/6/8/13/15): publish stores drained
// per-wave (vmcnt0) + barrier before tid0's RMW; RMW round-trip precedes
// done visibility; consumers poll done (tid0 only), read relaxed agent.

typedef unsigned short u16;
typedef unsigned int   u32;
typedef unsigned long long u64;
typedef __bf16 bf16x8 __attribute__((ext_vector_type(8)));
typedef float  f32x4  __attribute__((ext_vector_type(4)));

__device__ __forceinline__ u16 f2b(float f) {
  __hip_bfloat16 h = __float2bfloat16(f);
  return __builtin_bit_cast(u16, h);
}
__device__ __forceinline__ float b2f(u16 u) {
  return __bfloat162float(__builtin_bit_cast(__hip_bfloat16, u));
}

__device__ __forceinline__ void gload16(const void* g, void* lds) {
  __builtin_amdgcn_global_load_lds(
      (const __attribute__((address_space(1))) u32*)g,
      (__attribute__((address_space(3))) u32*)lds, 16, 0, 0);
}

__device__ __forceinline__ u64 aload64(const u64* p) {
  return __hip_atomic_load(p, __ATOMIC_RELAXED, __HIP_MEMORY_SCOPE_AGENT);
}
__device__ __forceinline__ void astore64(u64* p, u64 v) {
  __hip_atomic_store(p, v, __ATOMIC_RELAXED, __HIP_MEMORY_SCOPE_AGENT);
}
__device__ __forceinline__ int aloadi(const int* p) {
  return __hip_atomic_load(p, __ATOMIC_RELAXED, __HIP_MEMORY_SCOPE_AGENT);
}
__device__ __forceinline__ void astorei(int* p, int v) {
  __hip_atomic_store(p, v, __ATOMIC_RELAXED, __HIP_MEMORY_SCOPE_AGENT);
}
__device__ __forceinline__ int afetchadd(int* p) {
  return __hip_atomic_fetch_add(p, 1, __ATOMIC_RELAXED,
                                __HIP_MEMORY_SCOPE_AGENT);
}

// Stage 16 rows x 2048B with 1024 threads (coalesced agent loads; XOR
// swizzle byte^=((row&7)<<4)).  4 loads/thread; each 256-thread slab
// covers one contiguous 2KB row per step.
__device__ __forceinline__ void stage16_1024(char* hbuf, const u64* src,
                                             int tid) {
  const int rsub = tid >> 8;       // 0..3
  const int coff = tid & 255;      // u64 within row
  u64 tmp[4];
#pragma unroll
  for (int i = 0; i < 4; ++i) {
    int it = i * 4 + rsub;
    tmp[i] = aload64(src + it * 256 + coff);
  }
#pragma unroll
  for (int i = 0; i < 4; ++i) {
    int it = i * 4 + rsub;
    *(u64*)(hbuf + it * 2048 + ((coff * 8) ^ ((it & 7) << 4))) = tmp[i];
  }
}

// ---------------------------------------------------------------- prep
__device__ __forceinline__ void cvt4(const float* __restrict__ s,
                                     u16* __restrict__ d, int n4,
                                     int gid, int stride) {
  for (int i = gid; i < n4; i += stride) {
    float4 f = ((const float4*)s)[i];
    ushort4 u;
    u.x = f2b(f.x); u.y = f2b(f.y); u.z = f2b(f.z); u.w = f2b(f.w);
    ((ushort4*)d)[i] = u;
  }
}

__global__ __launch_bounds__(256) void prep_kernel(
    const int* __restrict__ inputs, const float* __restrict__ hidden,
    const float* __restrict__ emb,
    const float* __restrict__ Wx0, const float* __restrict__ Wh0,
    const float* __restrict__ Wx1, const float* __restrict__ Wh1,
    const float* __restrict__ Wout,
    u16* Wx0b, u16* Wh0b, u16* Wcat1, u16* Woutb,
    u16* A0b, u16* Hh0, u16* Hh1, int* flags) {
  int gid = blockIdx.x * 256 + threadIdx.x;
  int stride = gridDim.x * 256;
  if (gid < 1024) flags[gid] = 0;
  cvt4(Wx0, Wx0b, 1024 * 512 / 4, gid, stride);
  cvt4(Wh0, Wh0b, 1024 * 1024 / 4, gid, stride);
  cvt4(Wout, Woutb, 10000 * 1024 / 4, gid, stride);
  cvt4(hidden, Hh0, 65536 / 4, gid, stride);            // slot 0 = h0 init
  cvt4(hidden + 65536, Hh1, 65536 / 4, gid, stride);    // slot 0 = h1 init
  // Wcat1[c][0..1023]=Wx1[c][:], [1024..2047]=Wh1[c][:]
  for (int i = gid; i < 1024 * 512; i += stride) {
    int row = i >> 9, j = i & 511;
    float4 f = (j < 256) ? ((const float4*)Wx1)[row * 256 + j]
                         : ((const float4*)Wh1)[row * 256 + (j - 256)];
    ushort4 u;
    u.x = f2b(f.x); u.y = f2b(f.y); u.z = f2b(f.z); u.w = f2b(f.w);
    ((ushort4*)Wcat1)[i] = u;
  }
  // embedding gather -> bf16 A0 (8192 x 512)
  for (int i = gid; i < 8192 * 128; i += stride) {
    int m = i >> 7, e4 = i & 127;
    int r = inputs[m];
    float4 f = ((const float4*)(emb + (size_t)r * 512))[e4];
    ushort4 u;
    u.x = f2b(f.x); u.y = f2b(f.y); u.z = f2b(f.z); u.w = f2b(f.w);
    ((ushort4*)A0b)[i] = u;
  }
}

// ---------------------------------------------------------------- GEMM (X0)
__global__ __launch_bounds__(256) void gemm_bt(
    const u16* __restrict__ A, const u16* __restrict__ Bm,
    const float* __restrict__ bias, u16* __restrict__ Cout,
    int M, int N, int K) {
  const int tid = threadIdx.x;
  const int l = tid & 63;
  const int wv = tid >> 6;
  const int MT = M >> 7;
  const int bm = (int)blockIdx.x % MT;
  const int bn = (int)blockIdx.x / MT;
  const int m0 = bm * 128, n0 = bn * 128;

  __shared__ u16 As[128 * 32];
  __shared__ u16 Bs[128 * 32];

  const int fa0 = wv * 1024 + l * 16;
  const int fa1 = (4 + wv) * 1024 + l * 16;
  const int rowA0 = fa0 >> 6, kO0 = (fa0 & 63) >> 1;
  const int rowA1 = fa1 >> 6, kO1 = (fa1 & 63) >> 1;
  const u16* gA0 = A + (size_t)(m0 + rowA0) * K + kO0;
  const u16* gA1 = A + (size_t)(m0 + rowA1) * K + kO1;
  const u16* gB0 = Bm + (size_t)(n0 + rowA0) * K + kO0;
  const u16* gB1 = Bm + (size_t)(n0 + rowA1) * K + kO1;
  u16* lA0 = As + wv * 512;
  u16* lA1 = As + (4 + wv) * 512;
  u16* lB0 = Bs + wv * 512;
  u16* lB1 = Bs + (4 + wv) * 512;

  const int wm = wv >> 1, wn = wv & 1;
  const u16* pA = As + (wm * 64 + (l & 15)) * 32 + (l >> 4) * 8;
  const u16* pB = Bs + (wn * 64 + (l & 15)) * 32 + (l >> 4) * 8;

  f32x4 acc[4][4] = {};

  for (int k0 = 0; k0 < K; k0 += 32) {
    __syncthreads();
    gload16(gA0 + k0, lA0);
    gload16(gA1 + k0, lA1);
    gload16(gB0 + k0, lB0);
    gload16(gB1 + k0, lB1);
    asm volatile("s_waitcnt vmcnt(0)" ::: "memory");
    __syncthreads();
    bf16x8 a[4], b[4];
#pragma unroll
    for (int i = 0; i < 4; ++i) a[i] = *(const bf16x8*)(pA + i * 512);
#pragma unroll
    for (int j = 0; j < 4; ++j) b[j] = *(const bf16x8*)(pB + j * 512);
#pragma unroll
    for (int i = 0; i < 4; ++i)
#pragma unroll
      for (int j = 0; j < 4; ++j)
        acc[i][j] = __builtin_amdgcn_mfma_f32_16x16x32_bf16(a[i], b[j],
                                                            acc[i][j], 0, 0, 0);
  }

#pragma unroll
  for (int j = 0; j < 4; ++j) {
    int cn = n0 + wn * 64 + j * 16 + (l & 15);
    float bv = bias[cn];
#pragma unroll
    for (int i = 0; i < 4; ++i) {
      int rmb = m0 + wm * 64 + i * 16 + ((l >> 4) << 2);
#pragma unroll
      for (int r = 0; r < 4; ++r)
        Cout[(size_t)(rmb + r) * N + cn] = f2b(acc[i][j][r] + bv);
    }
  }
}

// ------------------------------------------------ persistent fused kernel
// flags (ints, 64B lines): cnt0[bg]=+0, done0[bg]=+64, cnt1[bg]=+128,
//   done1[bg]=+256, dlog[bg]=+448, classq[c]=+640+(c<<4)   (idx << 4)
__global__ __launch_bounds__(1024, 4) void rnn_fused(
    const u16* __restrict__ X0, const u16* __restrict__ Wh0b,
    const u16* __restrict__ Wcat1, const float* __restrict__ bh1,
    u16* __restrict__ Hh0, u16* __restrict__ Hh1,
    const u16* __restrict__ Woutb, const float* __restrict__ bout,
    float* __restrict__ outL,
    float* __restrict__ hfin0, float* __restrict__ hfin1,
    int* __restrict__ flags) {
  __shared__ __align__(16) char smem[65664];
  const int tid = threadIdx.x;
  const int l = tid & 63;
  const int wv = tid >> 6;       // 0..15

  if (blockIdx.x < 32) {
    // ---------------- layer 0: 128 cols/block, 8 blocks/bg
    char* hbuf = smem;                                     // 32 KB
    float (*red)[16][16] = (float(*)[16][16])(smem + 32768);  // [8][16][16]
    u16* ht = (u16*)(smem + 40960);                        // 16x128 bf16
    const int wg = (int)blockIdx.x;
    const int bg = wg & 3, cc = wg >> 2;    // cc 0..7
    const int cw = wv & 7, kw = wv >> 3;    // col-eighth, K-half
    const int col = cc * 128 + cw * 16 + (l & 15);
    const int row = l & 15;
    const int sw = (row & 7) << 4;
    const int rowoff = row * 2048;
    const int kwbase = kw * 1024 + ((l >> 4) << 4);
    bf16x8 b[16];
    {
      const u16* wp = Wh0b + (size_t)col * 1024 + (kw * 512 + ((l >> 4) * 8));
#pragma unroll
      for (int kt = 0; kt < 16; ++kt) b[kt] = *(const bf16x8*)(wp + kt * 32);
    }
    int* cnt0 = flags + (bg << 4);
    int* done0 = flags + 64 + (bg << 4);

    for (int t = 0; t < 128; ++t) {
      float xv[4];
      if (kw == 0) {
#pragma unroll
        for (int r = 0; r < 4; ++r) {
          int bat = bg * 16 + (l >> 4) * 4 + r;
          xv[r] = b2f(X0[(size_t)(t * 64 + bat) * 1024 + col]);
        }
      }
      stage16_1024(hbuf, (const u64*)(Hh0 + ((size_t)t * 64 + bg * 16) * 1024),
                   tid);
      __syncthreads();
      f32x4 acc = {0.f, 0.f, 0.f, 0.f};
#pragma unroll
      for (int kt = 0; kt < 16; ++kt) {
        bf16x8 av =
            *(const bf16x8*)(hbuf + rowoff + ((kwbase + kt * 64) ^ sw));
        acc = __builtin_amdgcn_mfma_f32_16x16x32_bf16(av, b[kt], acc, 0, 0, 0);
      }
      if (kw == 1) {
#pragma unroll
        for (int r = 0; r < 4; ++r) red[cw][(l >> 4) * 4 + r][l & 15] = acc[r];
      }
      __syncthreads();
      if (kw == 0) {
#pragma unroll
        for (int r = 0; r < 4; ++r) {
          int br = (l >> 4) * 4 + r;
          float v = acc[r] + red[cw][br][l & 15] + xv[r];
          v = tanhf(v);
          ht[br * 128 + cw * 16 + (l & 15)] = f2b(v);
          if (t == 127) hfin0[(bg * 16 + br) * 1024 + col] = v;
        }
      }
      __syncthreads();
      if (tid < 512) {  // publish 16 rows x 256B into Hh0[t+1]
        int rw = tid >> 5, seg = tid & 31;
        u64 v = ((const u64*)ht)[tid];
        u64* dp = (u64*)(Hh0 + ((size_t)(t + 1) * 64 + bg * 16 + rw) * 1024 +
                         cc * 128) + seg;
        astore64(dp, v);
      }
      asm volatile("s_waitcnt vmcnt(0)" ::: "memory");
      __syncthreads();  // all waves' publishes drained
      if (tid == 0) {
        int old = afetchadd(cnt0);
        if (old == (t + 1) * 8 - 1) {
          astorei(done0, t + 1);   // winner broadcast
        } else if (t < 127) {
          while (aloadi(done0) < t + 1) __builtin_amdgcn_s_sleep(1);
        }
      }
      __syncthreads();
    }
  } else if (blockIdx.x < 96) {
    // ---------------- layer 1: 64 cols/block, 16 blocks/bg, K=2048 concat
    char* hbuf = smem;                                     // 32 KB two-phase
    float (*red)[3][16][16] = (float(*)[3][16][16])(smem + 32768);  // [4][..]
    u16* ht = (u16*)(smem + 45056);                        // 16x64 bf16
    const int wg = (int)blockIdx.x - 32;
    const int bg = wg & 3, cc = wg >> 2;    // cc 0..15
    const int ch = wv & 3, kw = wv >> 2;    // col-quarter, K-quarter
    const int col = cc * 64 + ch * 16 + (l & 15);
    const int row = l & 15;
    const int sw = (row & 7) << 4;
    const int rowoff = row * 2048;
    const int kwb = (kw & 1) * 1024 + ((l >> 4) << 4);  // within 16-row buf
    bf16x8 b[16];
    {
      const u16* wp = Wcat1 + (size_t)col * 2048 + (kw * 512 + ((l >> 4) * 8));
#pragma unroll
      for (int kt = 0; kt < 16; ++kt) b[kt] = *(const bf16x8*)(wp + kt * 32);
    }
    const float bias = bh1[col];
    int* done0 = flags + 64 + (bg << 4);
    int* cnt1 = flags + 128 + (bg << 4);
    int* done1 = flags + 256 + (bg << 4);
    int* dlog = flags + 448 + (bg << 4);

    for (int s = 0; s < 128; ++s) {
      // gate 1: h0[s] ready (L0 runs ahead -> usually instant)
      if (tid == 0) {
        while (aloadi(done0) < s + 1) __builtin_amdgcn_s_sleep(1);
      }
      __syncthreads();
      // phase A: stage h0[s] (= Hh0 slot s+1); waves kw<2 compute —
      // runs under the peer-straggler wait (gate 2 below).
      stage16_1024(hbuf,
                   (const u64*)(Hh0 + ((size_t)(s + 1) * 64 + bg * 16) * 1024),
                   tid);
      __syncthreads();
      f32x4 acc = {0.f, 0.f, 0.f, 0.f};
      if (kw < 2) {
#pragma unroll
        for (int kt = 0; kt < 16; ++kt) {
          bf16x8 av = *(const bf16x8*)(hbuf + rowoff + ((kwb + kt * 64) ^ sw));
          acc =
              __builtin_amdgcn_mfma_f32_16x16x32_bf16(av, b[kt], acc, 0, 0, 0);
        }
      }
      __syncthreads();  // phase-A readers done
      // gate 2: h1[s-1] complete from all 16 peer blocks of this bg
      if (tid == 0) {
        while (aloadi(done1) < s) __builtin_amdgcn_s_sleep(1);
      }
      __syncthreads();
      // phase B: stage h1[s-1] (= Hh1 slot s); waves kw>=2 compute
      stage16_1024(hbuf, (const u64*)(Hh1 + ((size_t)s * 64 + bg * 16) * 1024),
                   tid);
      __syncthreads();
      if (kw >= 2) {
#pragma unroll
        for (int kt = 0; kt < 16; ++kt) {
          bf16x8 av = *(const bf16x8*)(hbuf + rowoff + ((kwb + kt * 64) ^ sw));
          acc =
              __builtin_amdgcn_mfma_f32_16x16x32_bf16(av, b[kt], acc, 0, 0, 0);
        }
      }
      if (kw != 0) {
#pragma unroll
        for (int r = 0; r < 4; ++r)
          red[ch][kw - 1][(l >> 4) * 4 + r][l & 15] = acc[r];
      }
      __syncthreads();
      if (kw == 0) {
#pragma unroll
        for (int r = 0; r < 4; ++r) {
          int br = (l >> 4) * 4 + r;
          int c = l & 15;
          float v = acc[r] + red[ch][0][br][c] + red[ch][1][br][c] +
                    red[ch][2][br][c] + bias;
          v = tanhf(v);
          ht[br * 64 + ch * 16 + c] = f2b(v);
          if (s == 127) hfin1[(bg * 16 + br) * 1024 + col] = v;
        }
      }
      __syncthreads();
      if (tid < 256) {  // publish 16 rows x 128B into Hh1[s+1]
        int rw = tid >> 4, seg = tid & 15;
        u64 v = ((const u64*)ht)[tid];
        u64* dp = (u64*)(Hh1 + ((size_t)(s + 1) * 64 + bg * 16 + rw) * 1024 +
                         cc * 64) + seg;
        astore64(dp, v);
      }
      asm volatile("s_waitcnt vmcnt(0)" ::: "memory");
      __syncthreads();
      if (tid == 0) {
        int old = afetchadd(cnt1);
        if (old == (s + 1) * 16 - 1) {
          astorei(done1, s + 1);   // for L1 peers
          astorei(dlog, s + 1);    // for logits workers (separate line)
        }
      }
    }
  } else {
    // ------- logits: 4 x 4-wave sub-workers; XCD-class tile queues
    const int sub = wv >> 2;        // 0..3
    const int wvl = wv & 3;         // wave within sub
    u16* As = (u16*)(smem + sub * 16384);
    u16* Bs = (u16*)(smem + sub * 16384 + 8192);
    int* shid = (int*)(smem + 65600);
    const int cls = ((int)blockIdx.x - 96) & 7;
    const int sz = (79 - cls + 7) / 8;            // tiles per u in class
    int* classq = flags + 640 + (cls << 4);
    int* dlg = flags + 448;

    const int fa0 = wvl * 1024 + l * 16;
    const int fa1 = (4 + wvl) * 1024 + l * 16;
    const int rowA0 = fa0 >> 6, kO0 = (fa0 & 63) >> 1;
    const int rowA1 = fa1 >> 6, kO1 = (fa1 & 63) >> 1;
    const u16* Abase = Hh1 + 65536;  // skip slot 0
    u16* lB0 = Bs + wvl * 512;
    u16* lB1 = Bs + (4 + wvl) * 512;
    u64* dA0 = (u64*)((char*)As + wvl * 1024 + l * 16);
    u64* dA1 = (u64*)((char*)As + (4 + wvl) * 1024 + l * 16);
    const int wm = wvl >> 1, wn = wvl & 1;
    const u16* pA = As + (wm * 64 + (l & 15)) * 32 + (l >> 4) * 8;
    const u16* pB = Bs + (wn * 64 + (l & 15)) * 32 + (l >> 4) * 8;

    for (;;) {
      if (tid == 0) *shid = afetchadd(classq);
      __syncthreads();
      const int base = *shid;
      __syncthreads();
      if (base >= 16 * sz) break;          // 64*sz tiles / 4 subs
      const int id = base * 4 + sub;
      const int u = id / sz, j = id - u * sz;
      const int nn = cls + j * 8;
      const int m0 = u * 128, n0 = nn * 128;

      if (tid == 0) {  // gate the highest-u sub tile of this grab
        const int umax = (base * 4 + 3) / sz;
        const int tgt = 2 * umax + 2;
        for (;;) {
          int ok = 1;
#pragma unroll
          for (int g = 0; g < 4; ++g) ok &= (aloadi(dlg + g * 16) >= tgt);
          if (ok) break;
          __builtin_amdgcn_s_sleep(32);
        }
      }
      __syncthreads();

      const u16* gA0 = Abase + (size_t)(m0 + rowA0) * 1024 + kO0;
      const u16* gA1 = Abase + (size_t)(m0 + rowA1) * 1024 + kO1;
      int rB0 = n0 + rowA0; if (rB0 >= 10000) rB0 = 9999;
      int rB1 = n0 + rowA1; if (rB1 >= 10000) rB1 = 9999;
      const u16* gB0 = Woutb + (size_t)rB0 * 1024 + kO0;
      const u16* gB1 = Woutb + (size_t)rB1 * 1024 + kO1;

      f32x4 acc[4][4] = {};
      for (int k0 = 0; k0 < 1024; k0 += 32) {
        __syncthreads();
        const u64* pa0 = (const u64*)(gA0 + k0);
        const u64* pa1 = (const u64*)(gA1 + k0);
        u64 a00 = aload64(pa0), a01 = aload64(pa0 + 1);
        u64 a10 = aload64(pa1), a11 = aload64(pa1 + 1);
        gload16(gB0 + k0, lB0);
        gload16(gB1 + k0, lB1);
        dA0[0] = a00; dA0[1] = a01;
        dA1[0] = a10; dA1[1] = a11;
        asm volatile("s_waitcnt vmcnt(0)" ::: "memory");
        __syncthreads();
        bf16x8 a[4], b[4];
#pragma unroll
        for (int i = 0; i < 4; ++i) a[i] = *(const bf16x8*)(pA + i * 512);
#pragma unroll
        for (int j2 = 0; j2 < 4; ++j2) b[j2] = *(const bf16x8*)(pB + j2 * 512);
#pragma unroll
        for (int i = 0; i < 4; ++i)
#pragma unroll
          for (int j2 = 0; j2 < 4; ++j2)
            acc[i][j2] = __builtin_amdgcn_mfma_f32_16x16x32_bf16(
                a[i], b[j2], acc[i][j2], 0, 0, 0);
      }
#pragma unroll
      for (int j2 = 0; j2 < 4; ++j2) {
        int cn = n0 + wn * 64 + j2 * 16 + (l & 15);
        if (cn >= 10000) continue;
        float bv = bout[cn];
#pragma unroll
        for (int i = 0; i < 4; ++i) {
          int rmb = m0 + wm * 64 + i * 16 + ((l >> 4) << 2);
#pragma unroll
          for (int r = 0; r < 4; ++r)
            outL[(size_t)(rmb + r) * 10000 + cn] = acc[i][j2][r] + bv;
        }
      }
    }
  }
}

// ---------------------------------------------------------------- launch
extern "C" void kernel_launch(void* const* d_in, const int* in_sizes, int n_in,
                              void* d_out, int out_size, void* d_ws,
                              size_t ws_size, hipStream_t stream) {
  const int*   inputs = (const int*)d_in[0];
  const float* hidden = (const float*)d_in[1];
  const float* emb    = (const float*)d_in[2];
  const float* Wx0    = (const float*)d_in[3];
  const float* Wh0    = (const float*)d_in[4];
  const float* bh0    = (const float*)d_in[5];
  const float* Wx1    = (const float*)d_in[6];
  const float* Wh1    = (const float*)d_in[7];
  const float* bh1    = (const float*)d_in[8];
  const float* Wout   = (const float*)d_in[9];
  const float* bout   = (const float*)d_in[10];
  float* out = (float*)d_out;

  if (ws_size < (size_t)88 * 1024 * 1024) return;

  char* w = (char*)d_ws;
  u16* Wx0b  = (u16*)w; w += 1048576;     // 1024x512
  u16* Wh0b  = (u16*)w; w += 2097152;     // 1024x1024
  u16* Wcat1 = (u16*)w; w += 4194304;     // 1024x2048
  u16* Woutb = (u16*)w; w += 20480000;    // 10000x1024
  u16* A0b   = (u16*)w; w += 8388608;     // 8192x512
  u16* X0b   = (u16*)w; w += 16777216;    // 8192x1024
  u16* Hh0   = (u16*)w; w += 16908288;    // 129x64x1024
  u16* Hh1   = (u16*)w; w += 16908288;    // 129x64x1024
  int* flags = (int*)w;                   // 1024 ints

  float* hfin0 = out + 81920000;
  float* hfin1 = out + 81920000 + 65536;

  prep_kernel<<<2048, 256, 0, stream>>>(inputs, hidden, emb, Wx0, Wh0, Wx1,
                                        Wh1, Wout, Wx0b, Wh0b, Wcat1, Woutb,
                                        A0b, Hh0, Hh1, flags);
  // X0 = emb_gathered @ Wx0^T + bh0   (8192 x 1024, K=512)
  gemm_bt<<<512, 256, 0, stream>>>(A0b, Wx0b, bh0, X0b, 8192, 1024, 512);
  // persistent: 2-layer recurrence + overlapped logits GEMM
  rnn_fused<<<256, 1024, 0, stream>>>(X0b, Wh0b, Wcat1, bh1, Hh0, Hh1, Woutb,
                                      bout, out, hfin0, hfin1, flags);
}